// Round 19
// baseline (24.237 us; speedup 1.0000x reference)
//
#include <hip/hip_runtime.h>
#include <hip/hip_bf16.h>

#define NQ 8
#define DIM 256
#define NL 3
#define BATCH 16384

using bf16x8 = __attribute__((ext_vector_type(8))) short;
using f32x4  = __attribute__((ext_vector_type(4))) float;

static __device__ __forceinline__ unsigned short f2bf(float f) {
    union { __hip_bfloat16 b; unsigned short u; } cv;
    cv.b = __float2bfloat16(f);
    return cv.u;
}

#define RYPAIR(c0, c1)                                                  \
    {                                                                   \
        float lr = re[c0], li = im[c0], hr = re[c1], hi = im[c1];       \
        re[c0] = cc * lr - s * hr;  im[c0] = cc * li - s * hi;          \
        re[c1] = s * lr + cc * hr;  im[c1] = s * li + cc * hi;          \
    }

// Gate-table LDS loader: 48 sincos pairs + 8 argmax rows (r11-verified).
#define LOAD_TABLES()                                                   \
    if (t < NL * NQ) {                                                  \
        float s, c; sincosf(0.5f * theta[t], &s, &c);                   \
        ths[t] = s; thc[t] = c;                                         \
    } else if (t < 2 * NL * NQ) {                                       \
        int i = t - NL * NQ;                                            \
        float s, c; sincosf(0.5f * omega[i], &s, &c);                   \
        oms[i] = s; omc[i] = c;                                         \
    } else if (t < 2 * NL * NQ + NQ) {                                  \
        int i = t - 2 * NL * NQ;                                        \
        const float* row = attn_w + i * NQ;                             \
        int best = 0; float bv = row[0];                                \
        _Pragma("unroll")                                               \
        for (int t2 = 1; t2 < NQ; ++t2) {                               \
            float v = row[t2];                                          \
            if (v > bv) { bv = v; best = t2; }                          \
        }                                                               \
        tgt_l[i] = best;                                                \
    }

// Gate-chain BODY, parameterized on coefficient lookups (r18-verified).
#define RUN_LAYERS_BODY(LANE, THS, THC, OMS, OMC, TGT, LAYER_PRAGMA)              \
    LAYER_PRAGMA                                                                  \
    for (int layer = 0; layer < NL; ++layer) {                                    \
        _Pragma("unroll")                                                         \
        for (int q = 0; q < NQ; ++q) {                                            \
            float s = THS[layer * NQ + q], cc = THC[layer * NQ + q];              \
            const int mask = 1 << (7 - q);                                        \
            if (mask == 128)      { RYPAIR(0, 2); RYPAIR(1, 3); }                 \
            else if (mask == 64)  { RYPAIR(0, 1); RYPAIR(2, 3); }                 \
            else {                                                                \
                _Pragma("unroll")                                                 \
                for (int c = 0; c < 4; ++c) {                                     \
                    float pr = __shfl_xor(re[c], mask);                           \
                    float pi = __shfl_xor(im[c], mask);                           \
                    if ((LANE) & mask) { re[c] = s * pr + cc * re[c]; im[c] = s * pi + cc * im[c]; } \
                    else               { re[c] = cc * re[c] - s * pr; im[c] = cc * im[c] - s * pi; } \
                }                                                                 \
            }                                                                     \
        }                                                                         \
        _Pragma("unroll")                                                         \
        for (int i = 0; i < NQ; ++i) {                                            \
            int t2 = TGT[i];                                                      \
            if (t2 == i) continue;                                                \
            int cmask = 1 << (7 - i);                                             \
            int tmask = 1 << (7 - t2);                                            \
            if (tmask == 128) {                                                   \
                int j0 = (LANE), j1 = 64 + (LANE), j2 = 128 + (LANE), j3 = 192 + (LANE); \
                bool k0 = (j0 & cmask), k1 = (j1 & cmask), k2 = (j2 & cmask), k3 = (j3 & cmask); \
                float n0r = k0 ? re[2] : re[0], n0i = k0 ? im[2] : im[0];         \
                float n1r = k1 ? re[3] : re[1], n1i = k1 ? im[3] : im[1];         \
                float n2r = k2 ? re[0] : re[2], n2i = k2 ? im[0] : im[2];         \
                float n3r = k3 ? re[1] : re[3], n3i = k3 ? im[1] : im[3];         \
                re[0] = n0r; im[0] = n0i; re[1] = n1r; im[1] = n1i;               \
                re[2] = n2r; im[2] = n2i; re[3] = n3r; im[3] = n3i;               \
            } else if (tmask == 64) {                                             \
                int j0 = (LANE), j1 = 64 + (LANE), j2 = 128 + (LANE), j3 = 192 + (LANE); \
                bool k0 = (j0 & cmask), k1 = (j1 & cmask), k2 = (j2 & cmask), k3 = (j3 & cmask); \
                float n0r = k0 ? re[1] : re[0], n0i = k0 ? im[1] : im[0];         \
                float n1r = k1 ? re[0] : re[1], n1i = k1 ? im[0] : im[1];         \
                float n2r = k2 ? re[3] : re[2], n2i = k2 ? im[3] : im[2];         \
                float n3r = k3 ? re[2] : re[3], n3i = k3 ? im[2] : im[3];         \
                re[0] = n0r; im[0] = n0i; re[1] = n1r; im[1] = n1i;               \
                re[2] = n2r; im[2] = n2i; re[3] = n3r; im[3] = n3i;               \
            } else {                                                              \
                _Pragma("unroll")                                                 \
                for (int c = 0; c < 4; ++c) {                                     \
                    int j = c * 64 + (LANE);                                      \
                    float pr = __shfl_xor(re[c], tmask);                          \
                    float pi = __shfl_xor(im[c], tmask);                          \
                    bool take = (j & cmask) != 0;                                 \
                    re[c] = take ? pr : re[c];                                    \
                    im[c] = take ? pi : im[c];                                    \
                }                                                                 \
            }                                                                     \
        }                                                                         \
        _Pragma("unroll")                                                         \
        for (int q = 0; q < NQ; ++q) {                                            \
            float sa = OMS[layer * NQ + q], ca = OMC[layer * NQ + q];             \
            const int mask = 1 << (7 - q);                                        \
            _Pragma("unroll")                                                     \
            for (int c = 0; c < 4; ++c) {                                         \
                int j = c * 64 + (LANE);                                          \
                float sb = (j & mask) ? sa : -sa;                                 \
                float r2 = re[c] * ca - im[c] * sb;                               \
                float i2 = re[c] * sb + im[c] * ca;                               \
                re[c] = r2; im[c] = i2;                                           \
            }                                                                     \
        }                                                                         \
    }

#define NOP_PRAGMA
#define RUN_LAYERS_LDS(LANE) \
    RUN_LAYERS_BODY(LANE, ths, thc, oms, omc, tgt_l, NOP_PRAGMA)

// Bf store in MFMA-fragment order (r9-verified).
#define STORE_BF_SLICE(K, LANE)                                         \
    {                                                                   \
        const int kbase = ((K) >> 5) * 32;                              \
        const int lg16  = (((K) >> 3) & 3) * 16;                        \
        const int e     = (K) & 7;                                      \
        _Pragma("unroll")                                               \
        for (int c = 0; c < 4; ++c) {                                   \
            int j  = c * 64 + (LANE);                                   \
            int n0 = 2 * j, n1 = 2 * j + 1;                             \
            size_t o0 = ((size_t)(kbase + (n0 >> 4)) * 64 + lg16 + (n0 & 15)) * 8 + e; \
            size_t o1 = ((size_t)(kbase + (n1 >> 4)) * 64 + lg16 + (n1 & 15)) * 8 + e; \
            Bf[o0] = f2bf(im[c]);   /* even n: imag (H-IMRE) */         \
            Bf[o1] = f2bf(re[c]);   /* odd  n: real */                  \
        }                                                               \
    }

// ---------------------------------------------------------------------------
// Kernel 1: build B — r18 EXACT (register-preloaded tables, unrolled chain).
// ---------------------------------------------------------------------------
__global__ __launch_bounds__(256) void build_B_kernel(
    const float* __restrict__ theta, const float* __restrict__ omega,
    const float* __restrict__ attn_w, unsigned short* __restrict__ Bf)
{
    __shared__ float thc[NL * NQ], ths[NL * NQ], omc[NL * NQ], oms[NL * NQ];
    __shared__ int   tgt_l[NQ];
    const int t = threadIdx.x;
    LOAD_TABLES();
    __syncthreads();

    float r_ths[NL * NQ], r_thc[NL * NQ], r_oms[NL * NQ], r_omc[NL * NQ];
    int   r_tgt[NQ];
    #pragma unroll
    for (int i = 0; i < NL * NQ; ++i) {
        r_ths[i] = ths[i]; r_thc[i] = thc[i];
        r_oms[i] = oms[i]; r_omc[i] = omc[i];
    }
    #pragma unroll
    for (int i = 0; i < NQ; ++i) r_tgt[i] = tgt_l[i];

    const int lane = t & 63;
    const int k = blockIdx.x * 4 + (t >> 6);
    float re[4], im[4];
    #pragma unroll
    for (int c = 0; c < 4; ++c) {
        re[c] = (c * 64 + lane == k) ? 1.0f : 0.0f;
        im[c] = 0.0f;
    }

    RUN_LAYERS_BODY(lane, r_ths, r_thc, r_oms, r_omc, r_tgt, _Pragma("unroll"));

    STORE_BF_SLICE(k, lane);
}

// ---------------------------------------------------------------------------
// Kernel 2, ROUND 19: r18 gemm with Bf PREFETCH AT KERNEL ENTRY.
// The 32 bfrag dwordx4 loads depend on nothing computed in-kernel; issuing
// them first hides their L2 latency (~300cy each, previously exposed in
// phase 3) under the sincos/product staging (~1-2 µs). Pure load reorder:
// same addresses, same data, bit-identical math. All indices compile-time.
// ---------------------------------------------------------------------------
__global__ __launch_bounds__(512) void gemm_kernel(
    const float* __restrict__ x, const unsigned short* __restrict__ Bf,
    unsigned short* __restrict__ out)
{
    __shared__ unsigned short A_lds[64][264];
    __shared__ float trig[64][NQ][2];
    const int t = threadIdx.x;
    const int b0 = blockIdx.x * 64;
    const int w = t >> 6;
    const int l = t & 63;
    const int lrow = l & 15, lgrp = l >> 4;

    // ---- Bf prefetch: all 8 ks-steps x 4 ntiles, issued before staging ----
    bf16x8 bfrag[8][4];
    #pragma unroll
    for (int ks = 0; ks < 8; ++ks)
        #pragma unroll
        for (int nt = 0; nt < 4; ++nt)
            bfrag[ks][nt] = *(const bf16x8*)&Bf[((size_t)(ks * 32 + w * 4 + nt) * 64 + l) * 8];

    {   // sincos: one (sample, qubit) per thread (r9/r11-verified)
        int b = t >> 3, q = t & 7;
        float a = 0.5f * x[(size_t)(b0 + b) * NQ + q];
        float s, c; sincosf(a, &s, &c);
        trig[b][q][0] = c; trig[b][q][1] = s;
    }
    __syncthreads();

    {   // product state S[b][j]: 8 threads/sample, 32 j's each (r9/r11-verified)
        int b = t >> 3;
        int j0 = (t & 7) * 32;
        float cq[NQ], sq[NQ];
        #pragma unroll
        for (int q = 0; q < NQ; ++q) { cq[q] = trig[b][q][0]; sq[q] = trig[b][q][1]; }
        float hi3 = (((j0 >> 7) & 1) ? sq[0] : cq[0]) *
                    (((j0 >> 6) & 1) ? sq[1] : cq[1]) *
                    (((j0 >> 5) & 1) ? sq[2] : cq[2]);
        float t3[8];
        #pragma unroll
        for (int h = 0; h < 8; ++h)
            t3[h] = ((h & 4) ? sq[3] : cq[3]) * ((h & 2) ? sq[4] : cq[4]) * ((h & 1) ? sq[5] : cq[5]);
        float t2v[4];
        #pragma unroll
        for (int v2 = 0; v2 < 4; ++v2)
            t2v[v2] = ((v2 & 2) ? sq[6] : cq[6]) * ((v2 & 1) ? sq[7] : cq[7]);
        #pragma unroll
        for (int i = 0; i < 32; i += 2) {
            float v0 = hi3 * t3[i >> 2] * t2v[i & 3];
            float v1 = hi3 * t3[(i + 1) >> 2] * t2v[(i + 1) & 3];
            unsigned int pack = (unsigned int)f2bf(v0) | ((unsigned int)f2bf(v1) << 16);
            *(unsigned int*)&A_lds[b][j0 + i] = pack;
        }
    }
    __syncthreads();

    f32x4 acc[4][4];
    #pragma unroll
    for (int m = 0; m < 4; ++m)
        #pragma unroll
        for (int nt = 0; nt < 4; ++nt)
            acc[m][nt] = (f32x4){0.f, 0.f, 0.f, 0.f};

    #pragma unroll
    for (int ks = 0; ks < 8; ++ks) {
        bf16x8 afrag[4];
        #pragma unroll
        for (int m = 0; m < 4; ++m)
            afrag[m] = *(const bf16x8*)&A_lds[m * 16 + lrow][ks * 32 + lgrp * 8];
        #pragma unroll
        for (int m = 0; m < 4; ++m)
            #pragma unroll
            for (int nt = 0; nt < 4; ++nt)
                acc[m][nt] = __builtin_amdgcn_mfma_f32_16x16x32_bf16(
                    afrag[m], bfrag[ks][nt], acc[m][nt], 0, 0, 0);
    }

    #pragma unroll
    for (int m = 0; m < 4; ++m)
        #pragma unroll
        for (int nt = 0; nt < 4; ++nt)
            #pragma unroll
            for (int r = 0; r < 4; ++r) {
                int row = b0 + m * 16 + lgrp * 4 + r;
                int n = (w * 4 + nt) * 16 + lrow;
                out[(size_t)row * 512 + n] = f2bf(acc[m][nt][r]);
            }
}

// ---------------------------------------------------------------------------
// Fallback: r8's verified direct simulation (ws too small).
// ---------------------------------------------------------------------------
__global__ __launch_bounds__(256) void sim_kernel(
    const float* __restrict__ x, const float* __restrict__ theta,
    const float* __restrict__ omega, const float* __restrict__ attn_w,
    unsigned short* __restrict__ out)
{
    __shared__ float thc[NL * NQ], ths[NL * NQ], omc[NL * NQ], oms[NL * NQ];
    __shared__ int   tgt_l[NQ];
    const int t = threadIdx.x;
    LOAD_TABLES();
    __syncthreads();

    const int lane = t & 63;
    const int b = blockIdx.x * 4 + (t >> 6);

    float cq[NQ], sq[NQ];
    #pragma unroll
    for (int q = 0; q < NQ; ++q) {
        float a = 0.5f * x[(size_t)b * NQ + q];
        sincosf(a, &sq[q], &cq[q]);
    }
    float re[4], im[4];
    #pragma unroll
    for (int c = 0; c < 4; ++c) {
        int j = c * 64 + lane;
        float v = 1.0f;
        #pragma unroll
        for (int q = 0; q < NQ; ++q)
            v *= ((j >> (7 - q)) & 1) ? sq[q] : cq[q];
        re[c] = v; im[c] = 0.0f;
    }
    RUN_LAYERS_LDS(lane);
    #pragma unroll
    for (int c = 0; c < 4; ++c) {
        size_t elem = (size_t)b * DIM + c * 64 + lane;
        unsigned int pack = (unsigned int)f2bf(im[c]) | ((unsigned int)f2bf(re[c]) << 16);
        *(unsigned int*)&out[elem * 2] = pack;
    }
}

extern "C" void kernel_launch(void* const* d_in, const int* in_sizes, int n_in,
                              void* d_out, int out_size, void* d_ws, size_t ws_size,
                              hipStream_t stream) {
    const float* x      = (const float*)d_in[0];
    const float* theta  = (const float*)d_in[1];
    const float* omega  = (const float*)d_in[2];
    const float* attn_w = (const float*)d_in[3];
    unsigned short* outp = (unsigned short*)d_out;

    const size_t B_BYTES = (size_t)DIM * 512 * 2;   // 256 KB fragment-ordered B
    if (ws_size >= B_BYTES) {
        unsigned short* Bf = (unsigned short*)d_ws;
        build_B_kernel<<<DIM / 4, 256, 0, stream>>>(theta, omega, attn_w, Bf);
        gemm_kernel<<<BATCH / 64, 512, 0, stream>>>(x, Bf, outp);
    } else {
        sim_kernel<<<BATCH / 4, 256, 0, stream>>>(x, theta, omega, attn_w, outp);
    }
}

// Round 20
// 23.574 us; speedup vs baseline: 1.0281x; 1.0281x over previous
//
#include <hip/hip_runtime.h>
#include <hip/hip_bf16.h>

#define NQ 8
#define DIM 256
#define NL 3
#define BATCH 16384

using bf16x8 = __attribute__((ext_vector_type(8))) short;
using f32x4  = __attribute__((ext_vector_type(4))) float;

static __device__ __forceinline__ unsigned short f2bf(float f) {
    union { __hip_bfloat16 b; unsigned short u; } cv;
    cv.b = __float2bfloat16(f);
    return cv.u;
}

#define RYPAIR(c0, c1)                                                  \
    {                                                                   \
        float lr = re[c0], li = im[c0], hr = re[c1], hi = im[c1];       \
        re[c0] = cc * lr - s * hr;  im[c0] = cc * li - s * hi;          \
        re[c1] = s * lr + cc * hr;  im[c1] = s * li + cc * hi;          \
    }

// Gate-table LDS loader: 48 sincos pairs + 8 argmax rows (r11-verified).
#define LOAD_TABLES()                                                   \
    if (t < NL * NQ) {                                                  \
        float s, c; sincosf(0.5f * theta[t], &s, &c);                   \
        ths[t] = s; thc[t] = c;                                         \
    } else if (t < 2 * NL * NQ) {                                       \
        int i = t - NL * NQ;                                            \
        float s, c; sincosf(0.5f * omega[i], &s, &c);                   \
        oms[i] = s; omc[i] = c;                                         \
    } else if (t < 2 * NL * NQ + NQ) {                                  \
        int i = t - 2 * NL * NQ;                                        \
        const float* row = attn_w + i * NQ;                             \
        int best = 0; float bv = row[0];                                \
        _Pragma("unroll")                                               \
        for (int t2 = 1; t2 < NQ; ++t2) {                               \
            float v = row[t2];                                          \
            if (v > bv) { bv = v; best = t2; }                          \
        }                                                               \
        tgt_l[i] = best;                                                \
    }

// Gate-chain BODY, parameterized on coefficient lookups (r18-verified).
#define RUN_LAYERS_BODY(LANE, THS, THC, OMS, OMC, TGT, LAYER_PRAGMA)              \
    LAYER_PRAGMA                                                                  \
    for (int layer = 0; layer < NL; ++layer) {                                    \
        _Pragma("unroll")                                                         \
        for (int q = 0; q < NQ; ++q) {                                            \
            float s = THS[layer * NQ + q], cc = THC[layer * NQ + q];              \
            const int mask = 1 << (7 - q);                                        \
            if (mask == 128)      { RYPAIR(0, 2); RYPAIR(1, 3); }                 \
            else if (mask == 64)  { RYPAIR(0, 1); RYPAIR(2, 3); }                 \
            else {                                                                \
                _Pragma("unroll")                                                 \
                for (int c = 0; c < 4; ++c) {                                     \
                    float pr = __shfl_xor(re[c], mask);                           \
                    float pi = __shfl_xor(im[c], mask);                           \
                    if ((LANE) & mask) { re[c] = s * pr + cc * re[c]; im[c] = s * pi + cc * im[c]; } \
                    else               { re[c] = cc * re[c] - s * pr; im[c] = cc * im[c] - s * pi; } \
                }                                                                 \
            }                                                                     \
        }                                                                         \
        _Pragma("unroll")                                                         \
        for (int i = 0; i < NQ; ++i) {                                            \
            int t2 = TGT[i];                                                      \
            if (t2 == i) continue;                                                \
            int cmask = 1 << (7 - i);                                             \
            int tmask = 1 << (7 - t2);                                            \
            if (tmask == 128) {                                                   \
                int j0 = (LANE), j1 = 64 + (LANE), j2 = 128 + (LANE), j3 = 192 + (LANE); \
                bool k0 = (j0 & cmask), k1 = (j1 & cmask), k2 = (j2 & cmask), k3 = (j3 & cmask); \
                float n0r = k0 ? re[2] : re[0], n0i = k0 ? im[2] : im[0];         \
                float n1r = k1 ? re[3] : re[1], n1i = k1 ? im[3] : im[1];         \
                float n2r = k2 ? re[0] : re[2], n2i = k2 ? im[0] : im[2];         \
                float n3r = k3 ? re[1] : re[3], n3i = k3 ? im[1] : im[3];         \
                re[0] = n0r; im[0] = n0i; re[1] = n1r; im[1] = n1i;               \
                re[2] = n2r; im[2] = n2i; re[3] = n3r; im[3] = n3i;               \
            } else if (tmask == 64) {                                             \
                int j0 = (LANE), j1 = 64 + (LANE), j2 = 128 + (LANE), j3 = 192 + (LANE); \
                bool k0 = (j0 & cmask), k1 = (j1 & cmask), k2 = (j2 & cmask), k3 = (j3 & cmask); \
                float n0r = k0 ? re[1] : re[0], n0i = k0 ? im[1] : im[0];         \
                float n1r = k1 ? re[0] : re[1], n1i = k1 ? im[0] : im[1];         \
                float n2r = k2 ? re[3] : re[2], n2i = k2 ? im[3] : im[2];         \
                float n3r = k3 ? re[2] : re[3], n3i = k3 ? im[2] : im[3];         \
                re[0] = n0r; im[0] = n0i; re[1] = n1r; im[1] = n1i;               \
                re[2] = n2r; im[2] = n2i; re[3] = n3r; im[3] = n3i;               \
            } else {                                                              \
                _Pragma("unroll")                                                 \
                for (int c = 0; c < 4; ++c) {                                     \
                    int j = c * 64 + (LANE);                                      \
                    float pr = __shfl_xor(re[c], tmask);                          \
                    float pi = __shfl_xor(im[c], tmask);                          \
                    bool take = (j & cmask) != 0;                                 \
                    re[c] = take ? pr : re[c];                                    \
                    im[c] = take ? pi : im[c];                                    \
                }                                                                 \
            }                                                                     \
        }                                                                         \
        _Pragma("unroll")                                                         \
        for (int q = 0; q < NQ; ++q) {                                            \
            float sa = OMS[layer * NQ + q], ca = OMC[layer * NQ + q];             \
            const int mask = 1 << (7 - q);                                        \
            _Pragma("unroll")                                                     \
            for (int c = 0; c < 4; ++c) {                                         \
                int j = c * 64 + (LANE);                                          \
                float sb = (j & mask) ? sa : -sa;                                 \
                float r2 = re[c] * ca - im[c] * sb;                               \
                float i2 = re[c] * sb + im[c] * ca;                               \
                re[c] = r2; im[c] = i2;                                           \
            }                                                                     \
        }                                                                         \
    }

#define NOP_PRAGMA
#define RUN_LAYERS_LDS(LANE) \
    RUN_LAYERS_BODY(LANE, ths, thc, oms, omc, tgt_l, NOP_PRAGMA)

// Bf store in MFMA-fragment order (r9-verified).
#define STORE_BF_SLICE(K, LANE)                                         \
    {                                                                   \
        const int kbase = ((K) >> 5) * 32;                              \
        const int lg16  = (((K) >> 3) & 3) * 16;                        \
        const int e     = (K) & 7;                                      \
        _Pragma("unroll")                                               \
        for (int c = 0; c < 4; ++c) {                                   \
            int j  = c * 64 + (LANE);                                   \
            int n0 = 2 * j, n1 = 2 * j + 1;                             \
            size_t o0 = ((size_t)(kbase + (n0 >> 4)) * 64 + lg16 + (n0 & 15)) * 8 + e; \
            size_t o1 = ((size_t)(kbase + (n1 >> 4)) * 64 + lg16 + (n1 & 15)) * 8 + e; \
            Bf[o0] = f2bf(im[c]);   /* even n: imag (H-IMRE) */         \
            Bf[o1] = f2bf(re[c]);   /* odd  n: real */                  \
        }                                                               \
    }

// ---------------------------------------------------------------------------
// Kernel 1: build B — r18 EXACT (register-preloaded tables, unrolled chain).
// ---------------------------------------------------------------------------
__global__ __launch_bounds__(256) void build_B_kernel(
    const float* __restrict__ theta, const float* __restrict__ omega,
    const float* __restrict__ attn_w, unsigned short* __restrict__ Bf)
{
    __shared__ float thc[NL * NQ], ths[NL * NQ], omc[NL * NQ], oms[NL * NQ];
    __shared__ int   tgt_l[NQ];
    const int t = threadIdx.x;
    LOAD_TABLES();
    __syncthreads();

    float r_ths[NL * NQ], r_thc[NL * NQ], r_oms[NL * NQ], r_omc[NL * NQ];
    int   r_tgt[NQ];
    #pragma unroll
    for (int i = 0; i < NL * NQ; ++i) {
        r_ths[i] = ths[i]; r_thc[i] = thc[i];
        r_oms[i] = oms[i]; r_omc[i] = omc[i];
    }
    #pragma unroll
    for (int i = 0; i < NQ; ++i) r_tgt[i] = tgt_l[i];

    const int lane = t & 63;
    const int k = blockIdx.x * 4 + (t >> 6);
    float re[4], im[4];
    #pragma unroll
    for (int c = 0; c < 4; ++c) {
        re[c] = (c * 64 + lane == k) ? 1.0f : 0.0f;
        im[c] = 0.0f;
    }

    RUN_LAYERS_BODY(lane, r_ths, r_thc, r_oms, r_omc, r_tgt, _Pragma("unroll"));

    STORE_BF_SLICE(k, lane);
}

// ---------------------------------------------------------------------------
// Kernel 2: r11/r18 gemm EXACT (measured best: 23.78 µs total). Grid 256,
// 512 thr, M=64 x N=512; normal operand order; scalar 2B epilogue stores.
// Knobs measured-null and reverted: tile shape (r10), 2-blk/CU split (r13,
// tripwire), swapped-MFMA+uint2 epilogue (r15, -1.4µs), Bf entry prefetch
// (r19, -0.5µs). Fusion measured-closed: cross-block sync = 50-100µs (r12/r17).
// ---------------------------------------------------------------------------
__global__ __launch_bounds__(512) void gemm_kernel(
    const float* __restrict__ x, const unsigned short* __restrict__ Bf,
    unsigned short* __restrict__ out)
{
    __shared__ unsigned short A_lds[64][264];
    __shared__ float trig[64][NQ][2];
    const int t = threadIdx.x;
    const int b0 = blockIdx.x * 64;

    {
        int b = t >> 3, q = t & 7;
        float a = 0.5f * x[(size_t)(b0 + b) * NQ + q];
        float s, c; sincosf(a, &s, &c);
        trig[b][q][0] = c; trig[b][q][1] = s;
    }
    __syncthreads();

    {
        int b = t >> 3;
        int j0 = (t & 7) * 32;
        float cq[NQ], sq[NQ];
        #pragma unroll
        for (int q = 0; q < NQ; ++q) { cq[q] = trig[b][q][0]; sq[q] = trig[b][q][1]; }
        float hi3 = (((j0 >> 7) & 1) ? sq[0] : cq[0]) *
                    (((j0 >> 6) & 1) ? sq[1] : cq[1]) *
                    (((j0 >> 5) & 1) ? sq[2] : cq[2]);
        float t3[8];
        #pragma unroll
        for (int h = 0; h < 8; ++h)
            t3[h] = ((h & 4) ? sq[3] : cq[3]) * ((h & 2) ? sq[4] : cq[4]) * ((h & 1) ? sq[5] : cq[5]);
        float t2v[4];
        #pragma unroll
        for (int v2 = 0; v2 < 4; ++v2)
            t2v[v2] = ((v2 & 2) ? sq[6] : cq[6]) * ((v2 & 1) ? sq[7] : cq[7]);
        #pragma unroll
        for (int i = 0; i < 32; i += 2) {
            float v0 = hi3 * t3[i >> 2] * t2v[i & 3];
            float v1 = hi3 * t3[(i + 1) >> 2] * t2v[(i + 1) & 3];
            unsigned int pack = (unsigned int)f2bf(v0) | ((unsigned int)f2bf(v1) << 16);
            *(unsigned int*)&A_lds[b][j0 + i] = pack;
        }
    }
    __syncthreads();

    const int w = t >> 6;
    const int l = t & 63;
    const int lrow = l & 15, lgrp = l >> 4;
    f32x4 acc[4][4];
    #pragma unroll
    for (int m = 0; m < 4; ++m)
        #pragma unroll
        for (int nt = 0; nt < 4; ++nt)
            acc[m][nt] = (f32x4){0.f, 0.f, 0.f, 0.f};

    #pragma unroll
    for (int ks = 0; ks < 8; ++ks) {
        bf16x8 bfrag[4];
        #pragma unroll
        for (int nt = 0; nt < 4; ++nt)
            bfrag[nt] = *(const bf16x8*)&Bf[((size_t)(ks * 32 + w * 4 + nt) * 64 + l) * 8];
        bf16x8 afrag[4];
        #pragma unroll
        for (int m = 0; m < 4; ++m)
            afrag[m] = *(const bf16x8*)&A_lds[m * 16 + lrow][ks * 32 + lgrp * 8];
        #pragma unroll
        for (int m = 0; m < 4; ++m)
            #pragma unroll
            for (int nt = 0; nt < 4; ++nt)
                acc[m][nt] = __builtin_amdgcn_mfma_f32_16x16x32_bf16(
                    afrag[m], bfrag[nt], acc[m][nt], 0, 0, 0);
    }

    #pragma unroll
    for (int m = 0; m < 4; ++m)
        #pragma unroll
        for (int nt = 0; nt < 4; ++nt)
            #pragma unroll
            for (int r = 0; r < 4; ++r) {
                int row = b0 + m * 16 + lgrp * 4 + r;
                int n = (w * 4 + nt) * 16 + lrow;
                out[(size_t)row * 512 + n] = f2bf(acc[m][nt][r]);
            }
}

// ---------------------------------------------------------------------------
// Fallback: r8's verified direct simulation (ws too small).
// ---------------------------------------------------------------------------
__global__ __launch_bounds__(256) void sim_kernel(
    const float* __restrict__ x, const float* __restrict__ theta,
    const float* __restrict__ omega, const float* __restrict__ attn_w,
    unsigned short* __restrict__ out)
{
    __shared__ float thc[NL * NQ], ths[NL * NQ], omc[NL * NQ], oms[NL * NQ];
    __shared__ int   tgt_l[NQ];
    const int t = threadIdx.x;
    LOAD_TABLES();
    __syncthreads();

    const int lane = t & 63;
    const int b = blockIdx.x * 4 + (t >> 6);

    float cq[NQ], sq[NQ];
    #pragma unroll
    for (int q = 0; q < NQ; ++q) {
        float a = 0.5f * x[(size_t)b * NQ + q];
        sincosf(a, &sq[q], &cq[q]);
    }
    float re[4], im[4];
    #pragma unroll
    for (int c = 0; c < 4; ++c) {
        int j = c * 64 + lane;
        float v = 1.0f;
        #pragma unroll
        for (int q = 0; q < NQ; ++q)
            v *= ((j >> (7 - q)) & 1) ? sq[q] : cq[q];
        re[c] = v; im[c] = 0.0f;
    }
    RUN_LAYERS_LDS(lane);
    #pragma unroll
    for (int c = 0; c < 4; ++c) {
        size_t elem = (size_t)b * DIM + c * 64 + lane;
        unsigned int pack = (unsigned int)f2bf(im[c]) | ((unsigned int)f2bf(re[c]) << 16);
        *(unsigned int*)&out[elem * 2] = pack;
    }
}

extern "C" void kernel_launch(void* const* d_in, const int* in_sizes, int n_in,
                              void* d_out, int out_size, void* d_ws, size_t ws_size,
                              hipStream_t stream) {
    const float* x      = (const float*)d_in[0];
    const float* theta  = (const float*)d_in[1];
    const float* omega  = (const float*)d_in[2];
    const float* attn_w = (const float*)d_in[3];
    unsigned short* outp = (unsigned short*)d_out;

    const size_t B_BYTES = (size_t)DIM * 512 * 2;   // 256 KB fragment-ordered B
    if (ws_size >= B_BYTES) {
        unsigned short* Bf = (unsigned short*)d_ws;
        build_B_kernel<<<DIM / 4, 256, 0, stream>>>(theta, omega, attn_w, Bf);
        gemm_kernel<<<BATCH / 64, 512, 0, stream>>>(x, Bf, outp);
    } else {
        sim_kernel<<<BATCH / 4, 256, 0, stream>>>(x, theta, omega, attn_w, outp);
    }
}